// Round 6
// baseline (21.560 us; speedup 1.0000x reference)
//
#include <hip/hip_runtime.h>

// SingleCurveDeformLayer: 2-step Euler RBF flow, two kernels.
//   step1: shape1_i = land_i + TAU*sum_j exp(-|land_i - src_j|^2/s2)*mom_j   (all 2N i)
//   step2: out_i    = shape1_i + TAU*sum_j exp(-|shape1_i-shape1_j|^2/s2)*mom_j  (tgt i)
//
// Geometry: TPB=256 (4 waves), SPLIT=64 (c = lane), MP=4 points/lane,
// PPB = 16 points/block, NJ = 32 j-iters.
//   - each ds_read_b128 serves 64 lanes x 4 points = 256 pairs (2x R5:
//     R5's MP=2 made step1 LDS-pipe-bound at ~5.1us/CU; now ~2.56us)
//   - grid: step1 = 1024 blocks (4/CU, 16 waves/CU), step2 = 512 (2/CU)
//   - coords pre-scaled by sqrt(log2e/sigma^2) -> w = exp2(-(dx^2+dy^2)),
//     negation via free v_exp input modifier; TAU folded into momenta.

constexpr int N     = 2048;   // n_src == n_tgt
constexpr int TPB   = 256;    // 4 waves
constexpr int MP    = 4;      // i-points per lane
constexpr int PPB   = (TPB / 64) * MP;   // 16 points per block
constexpr int NJ    = N / 64;            // 32 j-iterations per lane
constexpr float TAU   = 0.5f;            // 1/(N_T-1), N_T=3
constexpr float LOG2E = 1.44269504088896340736f;

__device__ inline float exp2_neg(float x) {   // 2^(-x), free neg modifier
    return __builtin_amdgcn_exp2f(-x);
}

template<int STEP>
__global__ __launch_bounds__(TPB, 4)
void deform_kernel(const float* __restrict__ momentum,
                   const float* __restrict__ source_init,
                   const float* __restrict__ target_init,
                   const float* __restrict__ sigmaV2,
                   float* __restrict__ shape1,   // ws: [B][2N][2]
                   float* __restrict__ out)      // [B][N][2]
{
    __shared__ float4 sj[N];   // (s*x, s*y, TAU*mx, TAU*my): 32 KB

    const int tid  = threadIdx.x;
    const int ppb  = (STEP == 1) ? 2 * N : N;   // points per batch this step
    const int bpb  = ppb / PPB;                 // blocks per batch
    const int b    = blockIdx.x / bpb;
    const int pblk = blockIdx.x % bpb;

    const float scale = sqrtf(LOG2E / sigmaV2[0]);   // coord pre-scale

    // ---- stage source j-data into LDS (float4 = 2 points per load) ----
    for (int k4 = tid; k4 < N / 2; k4 += TPB) {      // 4 iters
        float4 p;
        if (STEP == 1) p = ((const float4*)source_init)[b * (N / 2) + k4];
        else           p = ((const float4*)(shape1 + (size_t)b * 2 * N * 2))[k4];
        const float4 m = ((const float4*)momentum)[b * (N / 2) + k4];
        sj[2 * k4 + 0] = make_float4(p.x * scale, p.y * scale, m.x * TAU, m.y * TAU);
        sj[2 * k4 + 1] = make_float4(p.z * scale, p.w * scale, m.z * TAU, m.w * TAU);
    }

    const int lane = tid & 63;           // j-chunk (full-wave split)
    const int g    = tid >> 6;           // wave id = point-group
    const int pi0  = pblk * PPB + g * MP;  // wave's 4 consecutive points

    // ---- wave's 4 i-positions (two float4 broadcasts) ----
    float4 pa, pb;
    if (STEP == 1) {
        if (pi0 < N) {
            pa = ((const float4*)source_init)[(b * N + pi0) >> 1];
            pb = ((const float4*)source_init)[(b * N + pi0 + 2) >> 1];
        } else {
            pa = ((const float4*)target_init)[(b * N + (pi0 - N)) >> 1];
            pb = ((const float4*)target_init)[(b * N + (pi0 - N) + 2) >> 1];
        }
    } else {
        pa = ((const float4*)shape1)[(b * 2 * N + N + pi0) >> 1];
        pb = ((const float4*)shape1)[(b * 2 * N + N + pi0 + 2) >> 1];
    }
    const float xs[MP] = {pa.x * scale, pa.z * scale, pb.x * scale, pb.z * scale};
    const float ys[MP] = {pa.y * scale, pa.w * scale, pb.y * scale, pb.w * scale};
    __syncthreads();

    float ax[MP] = {0.f, 0.f, 0.f, 0.f};
    float ay[MP] = {0.f, 0.f, 0.f, 0.f};
    #pragma unroll 4
    for (int t = 0; t < NJ; ++t) {
        const float4 s = sj[t * 64 + lane];
        #pragma unroll
        for (int m = 0; m < MP; ++m) {
            const float dx = xs[m] - s.x;
            const float dy = ys[m] - s.y;
            const float w  = exp2_neg(fmaf(dy, dy, dx * dx));
            ax[m] = fmaf(w, s.z, ax[m]);
            ay[m] = fmaf(w, s.w, ay[m]);
        }
    }

    // ---- reduce across all 64 lanes ----
    #pragma unroll
    for (int d = 1; d < 64; d <<= 1) {
        #pragma unroll
        for (int m = 0; m < MP; ++m) {
            ax[m] += __shfl_xor(ax[m], d);
            ay[m] += __shfl_xor(ay[m], d);
        }
    }

    if (lane == 0) {
        const float4 o0 = make_float4(pa.x + ax[0], pa.y + ay[0],
                                      pa.z + ax[1], pa.w + ay[1]);
        const float4 o1 = make_float4(pb.x + ax[2], pb.y + ay[2],
                                      pb.z + ax[3], pb.w + ay[3]);
        if (STEP == 1) {
            ((float4*)shape1)[(b * 2 * N + pi0) >> 1]     = o0;
            ((float4*)shape1)[(b * 2 * N + pi0 + 2) >> 1] = o1;
        } else {
            ((float4*)out)[(b * N + pi0) >> 1]     = o0;
            ((float4*)out)[(b * N + pi0 + 2) >> 1] = o1;
        }
    }
}

extern "C" void kernel_launch(void* const* d_in, const int* in_sizes, int n_in,
                              void* d_out, int out_size, void* d_ws, size_t ws_size,
                              hipStream_t stream)
{
    const float* momentum    = (const float*)d_in[0];
    const float* source_init = (const float*)d_in[1];
    const float* target_init = (const float*)d_in[2];
    const float* sigmaV2     = (const float*)d_in[3];
    float* out    = (float*)d_out;
    float* shape1 = (float*)d_ws;   // B * 4096 * 2 floats = 128 KB

    const int B = in_sizes[0] / (N * 2);   // 4

    dim3 blk(TPB);
    // step 1: all 2N landmarks per batch  -> B * 4096/16 = 1024 blocks
    deform_kernel<1><<<dim3(B * (2 * N / PPB)), blk, 0, stream>>>(
        momentum, source_init, target_init, sigmaV2, shape1, out);
    // step 2: target half only            -> B * 2048/16 = 512 blocks
    deform_kernel<2><<<dim3(B * (N / PPB)), blk, 0, stream>>>(
        momentum, source_init, target_init, sigmaV2, shape1, out);
}